// Round 1
// baseline (74.423 us; speedup 1.0000x reference)
//
#include <hip/hip_runtime.h>

// SmallTargetAwareLoss: fused weighted-BCE + dice over B=64, P=512*512.
// pred, target: fp32 [64, 1, 512, 512]. Output: 1 fp32 scalar.

#define B_SAMPLES 64
#define P_ELEMS   262144          // 512*512
#define P4        (P_ELEMS / 4)   // 65536 float4 per sample
#define BPS       16              // blocks per sample
#define TPB       256
#define CHUNK4    (P4 / BPS)      // 4096 float4 per block
#define ITERS     (CHUNK4 / TPB)  // 16 float4 per thread

__global__ __launch_bounds__(TPB) void stal_partial(
        const float* __restrict__ pred,
        const float* __restrict__ target,
        float* __restrict__ ws) {
    const int blk    = blockIdx.x;
    const int sample = blk / BPS;
    const int bin    = blk % BPS;
    const int tid    = threadIdx.x;

    const float4* p4 = reinterpret_cast<const float4*>(pred)
                       + (size_t)sample * P4 + (size_t)bin * CHUNK4;
    const float4* t4 = reinterpret_cast<const float4*>(target)
                       + (size_t)sample * P4 + (size_t)bin * CHUNK4;

    float s_bce = 0.f, s_pt = 0.f, s_p = 0.f, s_t = 0.f;

    for (int i = 0; i < ITERS; ++i) {
        float4 xv = p4[tid + i * TPB];
        float4 tv = t4[tid + i * TPB];
        #pragma unroll
        for (int j = 0; j < 4; ++j) {
            float x = (&xv.x)[j];
            float t = (&tv.x)[j];
            float ax  = fabsf(x);
            float e   = expf(-ax);              // shared by BCE tail and sigmoid
            float bce = fmaxf(x, 0.f) - x * t + log1pf(e);
            float pw  = fminf(1.f + 10.f * t, 20.f);
            s_bce += bce * pw;
            float inv = 1.f / (1.f + e);
            float p   = (x >= 0.f) ? inv : e * inv;   // sigmoid(x)
            s_p  += p;
            s_pt += p * t;
            s_t  += t;                          // t in {0,1} => also counts t>0.5
        }
    }

    // wave (64-lane) shuffle reduction
    for (int off = 32; off > 0; off >>= 1) {
        s_bce += __shfl_down(s_bce, off);
        s_pt  += __shfl_down(s_pt,  off);
        s_p   += __shfl_down(s_p,   off);
        s_t   += __shfl_down(s_t,   off);
    }

    __shared__ float red[4][4];   // 4 waves x 4 accumulators
    const int wave = tid >> 6;
    const int lane = tid & 63;
    if (lane == 0) {
        red[wave][0] = s_bce; red[wave][1] = s_pt;
        red[wave][2] = s_p;   red[wave][3] = s_t;
    }
    __syncthreads();
    if (tid == 0) {
        float a = 0.f, b = 0.f, c = 0.f, d = 0.f;
        for (int w = 0; w < 4; ++w) {
            a += red[w][0]; b += red[w][1]; c += red[w][2]; d += red[w][3];
        }
        float* o = ws + (size_t)blk * 4;
        o[0] = a; o[1] = b; o[2] = c; o[3] = d;   // every slot rewritten each launch
    }
}

__global__ __launch_bounds__(64) void stal_finalize(
        const float* __restrict__ ws,
        float* __restrict__ out) {
    const int b = threadIdx.x;   // sample id, 0..63 (one wave)

    float S0 = 0.f, S1 = 0.f, S2 = 0.f, S3 = 0.f;
    for (int k = 0; k < BPS; ++k) {
        const float* o = ws + ((size_t)b * BPS + k) * 4;
        S0 += o[0]; S1 += o[1]; S2 += o[2]; S3 += o[3];
    }

    const float invP = 1.f / (float)P_ELEMS;
    float area   = S3 * invP;
    bool  valid  = area < 0.05f;
    float wbce   = S0 * invP;
    float dice   = 1.f - (2.f * S1 + 1e-5f) / (S2 + S3 + 1e-5f);
    float loss   = 0.6f * wbce + 0.4f * dice;

    float v       = valid ? 1.f : 0.f;
    float contrib = valid ? loss : 0.f;
    for (int off = 32; off > 0; off >>= 1) {
        contrib += __shfl_down(contrib, off);
        v       += __shfl_down(v, off);
    }
    if (b == 0) {
        out[0] = (v > 0.f) ? contrib / fmaxf(v, 1.f) : 0.f;
    }
}

extern "C" void kernel_launch(void* const* d_in, const int* in_sizes, int n_in,
                              void* d_out, int out_size, void* d_ws, size_t ws_size,
                              hipStream_t stream) {
    const float* pred   = (const float*)d_in[0];
    const float* target = (const float*)d_in[1];
    float* out = (float*)d_out;
    float* ws  = (float*)d_ws;   // 64*16*4 floats = 16 KiB, all rewritten per launch

    stal_partial <<<B_SAMPLES * BPS, TPB, 0, stream>>>(pred, target, ws);
    stal_finalize<<<1, 64, 0, stream>>>(ws, out);
}

// Round 2
// 29.238 us; speedup vs baseline: 2.5454x; 2.5454x over previous
//
#include <hip/hip_runtime.h>

// SmallTargetAwareLoss: fused weighted-BCE + dice over B=64, P=512*512.
// pred, target: fp32 [64, 1, 512, 512]. Output: 1 fp32 scalar.
// R1: native-rate transcendentals (v_exp/v_log/v_rcp), 2048 blocks.

#define B_SAMPLES 64
#define P_ELEMS   262144          // 512*512
#define P4        (P_ELEMS / 4)   // 65536 float4 per sample
#define BPS       32              // blocks per sample
#define TPB       256
#define CHUNK4    (P4 / BPS)      // 2048 float4 per block
#define ITERS     (CHUNK4 / TPB)  // 8 float4 per thread

__global__ __launch_bounds__(TPB) void stal_partial(
        const float* __restrict__ pred,
        const float* __restrict__ target,
        float* __restrict__ ws) {
    const int blk    = blockIdx.x;
    const int sample = blk >> 5;          // / BPS
    const int bin    = blk & (BPS - 1);
    const int tid    = threadIdx.x;

    const float4* p4 = reinterpret_cast<const float4*>(pred)
                       + (size_t)sample * P4 + (size_t)bin * CHUNK4;
    const float4* t4 = reinterpret_cast<const float4*>(target)
                       + (size_t)sample * P4 + (size_t)bin * CHUNK4;

    float s_bce = 0.f, s_pt = 0.f, s_p = 0.f, s_t = 0.f;

    #pragma unroll
    for (int i = 0; i < ITERS; ++i) {
        float4 xv = p4[tid + i * TPB];
        float4 tv = t4[tid + i * TPB];
        #pragma unroll
        for (int j = 0; j < 4; ++j) {
            float x = (&xv.x)[j];
            float t = (&tv.x)[j];
            float ax = fabsf(x);
            float e  = __expf(-ax);                       // v_mul + v_exp_f32
            float r  = __builtin_amdgcn_rcpf(1.f + e);    // sigmoid(|x|)
            float p  = (x >= 0.f) ? r : 1.f - r;          // sigmoid(x)
            // bce = max(x,0) - x*t + log(1+e);  pos_weight = 1 + 10*t (t in {0,1})
            float bce = fmaxf(x, 0.f) - x * t + __logf(1.f + e);
            s_bce = fmaf(bce, fmaf(10.f, t, 1.f), s_bce);
            s_p  += p;
            s_pt  = fmaf(p, t, s_pt);
            s_t  += t;
        }
    }

    // wave (64-lane) shuffle reduction
    for (int off = 32; off > 0; off >>= 1) {
        s_bce += __shfl_down(s_bce, off);
        s_pt  += __shfl_down(s_pt,  off);
        s_p   += __shfl_down(s_p,   off);
        s_t   += __shfl_down(s_t,   off);
    }

    __shared__ float red[4][4];   // 4 waves x 4 accumulators
    const int wave = tid >> 6;
    const int lane = tid & 63;
    if (lane == 0) {
        red[wave][0] = s_bce; red[wave][1] = s_pt;
        red[wave][2] = s_p;   red[wave][3] = s_t;
    }
    __syncthreads();
    if (tid == 0) {
        float a = 0.f, b = 0.f, c = 0.f, d = 0.f;
        for (int w = 0; w < 4; ++w) {
            a += red[w][0]; b += red[w][1]; c += red[w][2]; d += red[w][3];
        }
        float* o = ws + (size_t)blk * 4;
        o[0] = a; o[1] = b; o[2] = c; o[3] = d;   // every slot rewritten each launch
    }
}

__global__ __launch_bounds__(64) void stal_finalize(
        const float* __restrict__ ws,
        float* __restrict__ out) {
    const int b = threadIdx.x;   // sample id, 0..63 (one wave)

    float S0 = 0.f, S1 = 0.f, S2 = 0.f, S3 = 0.f;
    for (int k = 0; k < BPS; ++k) {
        const float* o = ws + ((size_t)b * BPS + k) * 4;
        S0 += o[0]; S1 += o[1]; S2 += o[2]; S3 += o[3];
    }

    const float invP = 1.f / (float)P_ELEMS;
    float area   = S3 * invP;
    bool  valid  = area < 0.05f;
    float wbce   = S0 * invP;
    float dice   = 1.f - (2.f * S1 + 1e-5f) / (S2 + S3 + 1e-5f);
    float loss   = 0.6f * wbce + 0.4f * dice;

    float v       = valid ? 1.f : 0.f;
    float contrib = valid ? loss : 0.f;
    for (int off = 32; off > 0; off >>= 1) {
        contrib += __shfl_down(contrib, off);
        v       += __shfl_down(v, off);
    }
    if (b == 0) {
        out[0] = (v > 0.f) ? contrib / fmaxf(v, 1.f) : 0.f;
    }
}

extern "C" void kernel_launch(void* const* d_in, const int* in_sizes, int n_in,
                              void* d_out, int out_size, void* d_ws, size_t ws_size,
                              hipStream_t stream) {
    const float* pred   = (const float*)d_in[0];
    const float* target = (const float*)d_in[1];
    float* out = (float*)d_out;
    float* ws  = (float*)d_ws;   // 2048*4 floats = 32 KiB, all rewritten per launch

    stal_partial <<<B_SAMPLES * BPS, TPB, 0, stream>>>(pred, target, ws);
    stal_finalize<<<1, 64, 0, stream>>>(ws, out);
}